// Round 1
// baseline (98.727 us; speedup 1.0000x reference)
//
#include <hip/hip_runtime.h>

// n-step return: T=1024, B=4096, gamma=0.99, horizon=16, fp32 in/out.
// G[t,b] = sum_{h=0}^{15} g^h * rm[t+h,b]  (rm = rewards*masks, zero-padded past T)
//        + g^{min(t+16,T)-t} * values[min(t+15,T-1), b]
//
// Strategy: backward sliding-window recurrence W(t) = rm[t] + g*W(t+1) - g^16*rm[t+16],
// one column per thread, CT=32 timesteps per thread, 16-deep register circular buffer
// (indices const-fold under full unroll since t0 % 32 == 0). Memory-bound streaming:
// each input element read ~once (+15-row halo per chunk), coalesced along b.

constexpr int   T_DIM  = 1024;
constexpr int   B_DIM  = 4096;
constexpr int   H      = 16;     // horizon
constexpr int   CT     = 32;     // timesteps per thread
constexpr float GAMMA  = 0.99f;

constexpr float gpow_c(int n) {
    float g = 1.0f;
    for (int i = 0; i < n; ++i) g *= GAMMA;
    return g;
}
constexpr float G16 = gpow_c(16);

__global__ __launch_bounds__(256)
void NStepReturn_88691074662796_kernel(const float* __restrict__ rewards,
                                       const float* __restrict__ values,
                                       const float* __restrict__ masks,
                                       float* __restrict__ out)
{
    const int b  = blockIdx.x * 256 + threadIdx.x;        // column
    const int t0 = blockIdx.y * CT;                       // chunk start (multiple of 32)
    const int t_last = t0 + CT - 1;                       // <= T-1 by grid construction

    float buf[H];   // circular: buf[t & 15] holds rm[t] for the most recent 16 loads
    float W = 0.0f;

    // ---- init: W(t_last) = sum_{h=0}^{15} g^h * rm[t_last+h], fill circular buffer ----
    #pragma unroll
    for (int h = H - 1; h >= 0; --h) {
        const int t = t_last + h;                         // may exceed T-1 in last chunk
        float x = 0.0f;
        if (t < T_DIM) {
            x = rewards[t * B_DIM + b] * masks[t * B_DIM + b];
        }
        buf[(CT - 1 + h) & (H - 1)] = x;                  // == t & 15 (t0 % 16 == 0)
        W = x + GAMMA * W;                                // Horner: sum g^h x_h
    }

    // bootstrap helper: gb(t) = g^{min(t+16,T)-t}  (uniform branch; tail only in last chunk)
    {
        const int t = t_last;
        float gb = G16;
        if (t + H > T_DIM) {
            gb = 1.0f;
            for (int k = 0; k < T_DIM - t; ++k) gb *= GAMMA;
        }
        const int vi = min(t + H - 1, T_DIM - 1);
        out[t * B_DIM + b] = W + gb * values[vi * B_DIM + b];
    }

    // ---- backward sweep: W(t) = rm[t] + g*W(t+1) - g^16*rm[t+16] ----
    #pragma unroll
    for (int j = CT - 2; j >= 0; --j) {
        const int t = t0 + j;                             // always < T
        const float x16 = buf[j & (H - 1)];               // rm[t+16] (slot t & 15)
        const float x   = rewards[t * B_DIM + b] * masks[t * B_DIM + b];
        buf[j & (H - 1)] = x;
        W = x + GAMMA * W - G16 * x16;

        float gb = G16;
        if (t + H > T_DIM) {                              // only in last chunk's top 15 rows
            gb = 1.0f;
            for (int k = 0; k < T_DIM - t; ++k) gb *= GAMMA;
        }
        const int vi = min(t + H - 1, T_DIM - 1);
        out[t * B_DIM + b] = W + gb * values[vi * B_DIM + b];
    }
}

extern "C" void kernel_launch(void* const* d_in, const int* in_sizes, int n_in,
                              void* d_out, int out_size, void* d_ws, size_t ws_size,
                              hipStream_t stream) {
    const float* rewards = (const float*)d_in[0];
    const float* values  = (const float*)d_in[1];
    const float* masks   = (const float*)d_in[2];
    float* out = (float*)d_out;

    dim3 grid(B_DIM / 256, T_DIM / CT);   // (16, 32) = 512 blocks
    dim3 block(256);
    NStepReturn_88691074662796_kernel<<<grid, block, 0, stream>>>(rewards, values, masks, out);
}

// Round 2
// 89.816 us; speedup vs baseline: 1.0992x; 1.0992x over previous
//
#include <hip/hip_runtime.h>

// n-step return: T=1024, B=4096, gamma=0.99, horizon=16, fp32 in/out.
// G[t,b] = sum_{h=0}^{15} g^h * rm[t+h,b]  (rm = rewards*masks, zero-padded past T)
//        + g^{min(t+16,T)-t} * values[min(t+15,T-1), b]
//
// R1 analysis: latency-bound (VGPR=20, 2 loads in flight, 15% HBM BW).
// R2 strategy: CT=16 per thread, stage ALL loads (31 rows of r,m + 16 of v =
// 78 independent loads) into register arrays before computing — maximizes
// memory-level parallelism. 1024 blocks -> 16 waves/CU. Halo re-reads between
// adjacent chunks are absorbed by L2/L3 (measured: FETCH 32MB < 48MB compulsory).

constexpr int   T_DIM  = 1024;
constexpr int   B_DIM  = 4096;
constexpr int   H      = 16;     // horizon
constexpr int   CT     = 16;     // timesteps per thread
constexpr int   HALO   = H - 1;  // 15
constexpr int   ROWS   = CT + HALO;  // 31 staged rm rows
constexpr float GAMMA  = 0.99f;

constexpr float gpow_c(int n) {
    float g = 1.0f;
    for (int i = 0; i < n; ++i) g *= GAMMA;
    return g;
}
constexpr float G16 = gpow_c(16);

__global__ __launch_bounds__(256)
void NStepReturn_88691074662796_kernel(const float* __restrict__ rewards,
                                       const float* __restrict__ values,
                                       const float* __restrict__ masks,
                                       float* __restrict__ out)
{
    const int b  = blockIdx.x * 256 + threadIdx.x;        // column
    const int t0 = blockIdx.y * CT;                       // chunk start

    // ---- stage ALL global loads as independent ops (max loads-in-flight) ----
    float r[ROWS], m[ROWS], v[CT];
    #pragma unroll
    for (int i = 0; i < ROWS; ++i) {
        const int t = t0 + i;                             // may exceed T-1 in last chunk
        if (t < T_DIM) {
            r[i] = rewards[t * B_DIM + b];
            m[i] = masks[t * B_DIM + b];
        } else {
            r[i] = 0.0f;
            m[i] = 0.0f;
        }
    }
    #pragma unroll
    for (int i = 0; i < CT; ++i) {
        const int vi = min(t0 + i + H - 1, T_DIM - 1);
        v[i] = values[vi * B_DIM + b];
    }

    // ---- rm products (reuse r[]) ----
    #pragma unroll
    for (int i = 0; i < ROWS; ++i) r[i] *= m[i];

    // ---- init: W(t_last) = sum_{h=0}^{15} g^h rm[t_last+h] (Horner) ----
    float W = 0.0f;
    #pragma unroll
    for (int h = H - 1; h >= 0; --h) W = r[CT - 1 + h] + GAMMA * W;

    {   // bootstrap for t_last
        const int t = t0 + CT - 1;
        float gb = G16;
        if (t + H > T_DIM) {                              // uniform; last chunk only
            gb = 1.0f;
            for (int k = 0; k < T_DIM - t; ++k) gb *= GAMMA;
        }
        out[t * B_DIM + b] = W + gb * v[CT - 1];
    }

    // ---- backward sweep: W(t) = rm[t] + g*W(t+1) - g^16*rm[t+16] ----
    #pragma unroll
    for (int j = CT - 2; j >= 0; --j) {
        const int t = t0 + j;
        W = r[j] + GAMMA * W - G16 * r[j + H];

        float gb = G16;
        if (t + H > T_DIM) {                              // uniform; last chunk only
            gb = 1.0f;
            for (int k = 0; k < T_DIM - t; ++k) gb *= GAMMA;
        }
        out[t * B_DIM + b] = W + gb * v[j];
    }
}

extern "C" void kernel_launch(void* const* d_in, const int* in_sizes, int n_in,
                              void* d_out, int out_size, void* d_ws, size_t ws_size,
                              hipStream_t stream) {
    const float* rewards = (const float*)d_in[0];
    const float* values  = (const float*)d_in[1];
    const float* masks   = (const float*)d_in[2];
    float* out = (float*)d_out;

    dim3 grid(B_DIM / 256, T_DIM / CT);   // (16, 64) = 1024 blocks
    dim3 block(256);
    NStepReturn_88691074662796_kernel<<<grid, block, 0, stream>>>(rewards, values, masks, out);
}